// Round 20
// baseline (2039.763 us; speedup 1.0000x reference)
//
#include <hip/hip_runtime.h>
#include <stdint.h>

namespace {

constexpr int NIN = 21;
constexpr int T   = 3000;
constexpr int NB  = 2;     // batches per block -> 256 blocks = 1 per CU

constexpr float L2E  = 1.4426950408889634f;   // log2(e)
constexpr float L2E2 = 2.8853900817779268f;   // 2*log2(e)

typedef _Float16 f16x8 __attribute__((ext_vector_type(8)));
typedef float    f32x4 __attribute__((ext_vector_type(4)));

__device__ __forceinline__ float frcp(float x){ return __builtin_amdgcn_rcpf(x); }
// activations on pre-scaled gates: v = L2E*x (sigm) / L2E2*x (tanh)
__device__ __forceinline__ float sigm2(float v){ return frcp(1.0f + exp2f(-v)); }
__device__ __forceinline__ float tanh2(float v){
    return fmaf(-2.0f, frcp(exp2f(v) + 1.0f), 1.0f);
}
__device__ __forceinline__ float tanhc(float c){ return tanh2(c * L2E2); }

template<int CTRL>
__device__ __forceinline__ float dppf(float v){
    return __int_as_float(__builtin_amdgcn_update_dpp(
        0, __float_as_int(v), CTRL, 0xF, 0xF, true));
}
// Verified family: row_ror:J => out[i] = in[(i-J)&15]; row_shr:N => out[i] = in[i-N]
constexpr int SHR4  = 0x114;
constexpr int SHR8  = 0x118;
constexpr int SHR12 = 0x11C;
constexpr int ROR14 = 0x12E;   // out[i] = in[(i+2)&15]

#define MFMA(A,B,C) __builtin_amdgcn_mfma_f32_16x16x32_f16((A),(B),(C),0,0,0)

// LDS-visibility barrier WITHOUT vmcnt drain (keeps x prefetch in flight).
#define LDS_BARRIER() asm volatile("s_waitcnt lgkmcnt(0)\n\ts_barrier" ::: "memory")

__device__ __forceinline__ f16x8 ldfrag(const _Float16* p){
    return *reinterpret_cast<const f16x8*>(p);   // aligned 16B LDS read
}
__device__ __forceinline__ void cvt8h(const float* s, f16x8& hi){
    #pragma unroll
    for (int j=0;j<8;++j) hi[j] = (_Float16)s[j];
}

// Verified MFMA layout (r8-r18): D[n][m] = sum_k A[n][k]*B[m][k]
//   A-frag: n = lane&15, k = 32*kc + 8*(lane>>4) + j ; B same
//   D:      m = lane&15, n = 4*(lane>>4) + v
// B cols: 0,1 = batch0/1 Hhi; 2,3 = batch0/1 Hlo; >=4 zero.
// W f16 hi-only, pre-scaled (L2E / L2E2 for gate g).
// gate = D[:,m] + D[:,m+2] = Whi·(Hhi+Hlo). Bias 0.5x·sc in C-init.
// Spread via BUILTIN dpp movs only (r19's fused asm add-DPP read freshly
// written regs -> uninserted hazard nops -> wrong results. Never again.)
__device__ __forceinline__ void spread_fold(const f32x4& a0, const f32x4& a1,
                                            const f32x4& a2, const f32x4& a3,
                                            int q, float& g0, float& g1,
                                            float& g2, float& g3){
    float u1,u2,u3;
    u1=dppf<SHR4>(a0[1]); u2=dppf<SHR8>(a0[2]); u3=dppf<SHR12>(a0[3]);
    g0=(q==0)?a0[0]:(q==1)?u1:(q==2)?u2:u3;
    u1=dppf<SHR4>(a1[1]); u2=dppf<SHR8>(a1[2]); u3=dppf<SHR12>(a1[3]);
    g1=(q==0)?a1[0]:(q==1)?u1:(q==2)?u2:u3;
    u1=dppf<SHR4>(a2[1]); u2=dppf<SHR8>(a2[2]); u3=dppf<SHR12>(a2[3]);
    g2=(q==0)?a2[0]:(q==1)?u1:(q==2)?u2:u3;
    u1=dppf<SHR4>(a3[1]); u2=dppf<SHR8>(a3[2]); u3=dppf<SHR12>(a3[3]);
    g3=(q==0)?a3[0]:(q==1)?u1:(q==2)?u2:u3;
    g0 += dppf<ROR14>(g0);
    g1 += dppf<ROR14>(g1);
    g2 += dppf<ROR14>(g2);
    g3 += dppf<ROR14>(g3);
}

__launch_bounds__(512, 2)
__global__ void lstm_mfB(const float* __restrict__ x,
                         const float* __restrict__ Wih0, const float* __restrict__ Whh0,
                         const float* __restrict__ bih0, const float* __restrict__ bhh0,
                         const float* __restrict__ Wih1, const float* __restrict__ Whh1,
                         const float* __restrict__ bih1, const float* __restrict__ bhh1,
                         const float* __restrict__ Wfc,  const float* __restrict__ bfc,
                         float* __restrict__ out)
{
    const int tid  = threadIdx.x;
    const int lane = tid & 63;
    const int wid  = tid >> 6;
    const int c    = lane >> 4;     // k-subchunk 0..3
    const int mcol = lane & 15;
    const int b0   = blockIdx.x * NB;
    const bool isL0 = (wid < 4);
    const int  w    = wid & 3;      // unit range [16w, 16w+16)

    __shared__ __align__(16) _Float16 h1p[4][2][NB][72]; // [slot][plane][batch][unit(+pad)]
    __shared__ __align__(16) _Float16 h2p[4][2][NB][72];
    __shared__ __align__(16) _Float16 xp [4][2][NB][40]; // [slot][plane][batch][feat(+pad)]

    // ----- weights: unified slots, pre-scaled for exp2-based activations -----
    f16x8 Whi[4][4];
    f32x4 bias4[4];
    {
        float tmp[8];
        #pragma unroll
        for (int tau = 0; tau < 4; ++tau) {
            const float sc = (tau == 2) ? L2E2 : L2E;
            const int n = 64*tau + 16*w + mcol;
            if (isL0) {
                #pragma unroll
                for (int j=0;j<8;++j){ int k=8*c+j; tmp[j] = (k<NIN)? sc*Wih0[n*NIN+k] : 0.0f; }
                cvt8h(tmp, Whi[tau][0]);
                #pragma unroll
                for (int kc=0;kc<2;++kc){
                    #pragma unroll
                    for (int j=0;j<8;++j) tmp[j] = sc*Whh0[n*64 + 32*kc + 8*c + j];
                    cvt8h(tmp, Whi[tau][1+kc]);
                }
                #pragma unroll
                for (int j=0;j<8;++j) Whi[tau][3][j] = (_Float16)0.f;
            } else {
                #pragma unroll
                for (int kc=0;kc<2;++kc){
                    #pragma unroll
                    for (int j=0;j<8;++j) tmp[j] = sc*Wih1[n*64 + 32*kc + 8*c + j];
                    cvt8h(tmp, Whi[tau][kc]);
                }
                #pragma unroll
                for (int kc=0;kc<2;++kc){
                    #pragma unroll
                    for (int j=0;j<8;++j) tmp[j] = sc*Whh1[n*64 + 32*kc + 8*c + j];
                    cvt8h(tmp, Whi[tau][2+kc]);
                }
            }
            // bias: 0.5x (both summed cols carry it), scaled (r18 style: all cols)
            const int nb = 64*tau + 16*w + 4*c;
            #pragma unroll
            for (int v=0; v<4; ++v)
                bias4[tau][v] = 0.5f * sc * (isL0 ? (bih0[nb+v] + bhh0[nb+v])
                                                  : (bih1[nb+v] + bhh1[nb+v]));
        }
    }

    // ----- LDS zero init (slots 3 / (t-1) double as the t=0 zero states) -----
    {
        uint32_t* p1 = (uint32_t*)&h1p[0][0][0][0];   // 576 u32
        uint32_t* p2 = (uint32_t*)&h2p[0][0][0][0];
        uint32_t* p3 = (uint32_t*)&xp[0][0][0][0];    // 320 u32
        for (int i = tid; i < 576; i += 512){ p1[i]=0u; p2[i]=0u; }
        if (tid < 320) p3[tid] = 0u;
    }
    __syncthreads();

    // ----- x staging: waves 0,1, lane<NIN -> (batch=wid, feat=lane) -----
    const bool stg = (wid < 2) && (lane < NIN);
    const float* xsrc = x + (size_t)(b0 + (wid & 1)) * T * NIN + lane;
    float xq0 = 0.f, xq1 = 0.f, xq2 = 0.f, xq3 = 0.f;
    if (stg){
        float x0 = xsrc[0], x1 = xsrc[NIN];
        _Float16 hh0 = (_Float16)x0;
        xp[0][0][wid][lane] = hh0;
        xp[0][1][wid][lane] = (_Float16)(x0 - (float)hh0);
        _Float16 hh1 = (_Float16)x1;
        xp[1][0][wid][lane] = hh1;
        xp[1][1][wid][lane] = (_Float16)(x1 - (float)hh1);
        xq2 = xsrc[(size_t)2*NIN];   // consumed at t=0 (writes x(2))
        xq3 = xsrc[(size_t)3*NIN];   // consumed at t=1 (writes x(3))
    }
    __syncthreads();

    // ----- B fragments: lane mcol<4 -> batch = mcol&1, plane = mcol>>1 -----
    f16x8 Bf[4];
    #pragma unroll
    for (int kc=0;kc<4;++kc)
        #pragma unroll
        for (int j=0;j<8;++j) Bf[kc][j] = (_Float16)0.f;
    if (isL0 && mcol < 4){
        Bf[0] = ldfrag(&xp[0][mcol>>1][mcol&1][8*c]);   // x(0); h slots stay 0
    }

    float cst = 0.f;
    const int q   = mcol >> 2;
    const int m   = mcol & 1;
    const int pl  = (mcol >> 1) & 1;
    const int u   = 16*w + 4*c + q;
    const bool pw = ((mcol & 2) == 0);

    // ====== main loop: 750 x 4 phases; t = tb+ph in [0, T) ======
    for (int tb = 0; tb < T; tb += 4) {
        #pragma unroll
        for (int ph = 0; ph < 4; ++ph) {
            const int t = tb + ph;

            // ---- S1: issue x(t+4) global load into xq[ph] ----
            if (stg && (t + 4 < T)) {
                float v = xsrc[(size_t)(t+4)*NIN];
                if (ph == 0) xq0 = v; else if (ph == 1) xq1 = v;
                else if (ph == 2) xq2 = v; else xq3 = v;
            }

            // ---- S1: MFMA (Bf from prev phase) ----
            f32x4 a0 = MFMA(Whi[0][0], Bf[0], bias4[0]);
            f32x4 a1 = MFMA(Whi[1][0], Bf[0], bias4[1]);
            f32x4 a2 = MFMA(Whi[2][0], Bf[0], bias4[2]);
            f32x4 a3 = MFMA(Whi[3][0], Bf[0], bias4[3]);
            #pragma unroll
            for (int kc=1; kc<3; ++kc){
                a0 = MFMA(Whi[0][kc], Bf[kc], a0);
                a1 = MFMA(Whi[1][kc], Bf[kc], a1);
                a2 = MFMA(Whi[2][kc], Bf[kc], a2);
                a3 = MFMA(Whi[3][kc], Bf[kc], a3);
            }
            if (!isL0){   // wave-uniform: L1 has 4th chunk
                a0 = MFMA(Whi[0][3], Bf[3], a0);
                a1 = MFMA(Whi[1][3], Bf[3], a1);
                a2 = MFMA(Whi[2][3], Bf[3], a2);
                a3 = MFMA(Whi[3][3], Bf[3], a3);
            }

            // ---- spread (verified builtin-DPP path) + pointwise ----
            float g0,g1,g2,g3;
            spread_fold(a0,a1,a2,a3,q,g0,g1,g2,g3);

            _Float16 hh = (_Float16)0.f, hl = (_Float16)0.f;
            const bool dow = pw && (isL0 || t > 0);
            if (dow) {
                float i_ = sigm2(g0), f_ = sigm2(g1);
                float gg = tanh2(g2), o_ = sigm2(g3);
                cst = fmaf(f_, cst, i_ * gg);
                float h = o_ * tanhc(cst);
                hh = (_Float16)h;
                hl = (_Float16)(h - (float)hh);
            }

            // ---- S2: pre-barrier x-frag read (slot written 2 steps ago,
            //          protected by barrier(t-1); drains at LDS_BARRIER) ----
            if (isL0 && mcol < 4)
                Bf[0] = ldfrag(&xp[(ph+1) & 3][pl][m][8*c]);     // x(t+1)

            // ---- S2: writes ----
            if (dow) {
                if (isL0){
                    h1p[ph & 3][0][m][u] = hh;          // h1(t), slot t&3
                    h1p[ph & 3][1][m][u] = hl;
                } else {
                    h2p[(ph+3) & 3][0][m][u] = hh;      // h2(t-1), slot (t-1)&3
                    h2p[(ph+3) & 3][1][m][u] = hl;
                }
            }
            if (stg && (t + 2 < T)){
                float xv = (ph == 0) ? xq2 : (ph == 1) ? xq3
                         : (ph == 2) ? xq0 : xq1;       // xq[(ph+2)&3] = x(t+2)
                _Float16 xh = (_Float16)xv;
                xp[(ph+2) & 3][0][wid][lane] = xh;
                xp[(ph+2) & 3][1][wid][lane] = (_Float16)(xv - (float)xh);
            }

            LDS_BARRIER();   // writes (and x-frag read) retired; vmcnt NOT drained

            // ---- S3: h fragment reads for step t+1 ----
            if (mcol < 4){
                if (isL0){
                    Bf[1] = ldfrag(&h1p[ph & 3][pl][m][8*c]);        // h1(t)
                    Bf[2] = ldfrag(&h1p[ph & 3][pl][m][32 + 8*c]);
                } else {
                    Bf[0] = ldfrag(&h1p[ph & 3][pl][m][8*c]);        // h1(t)
                    Bf[1] = ldfrag(&h1p[ph & 3][pl][m][32 + 8*c]);
                    Bf[2] = ldfrag(&h2p[(ph+3) & 3][pl][m][8*c]);    // h2(t-1)
                    Bf[3] = ldfrag(&h2p[(ph+3) & 3][pl][m][32 + 8*c]);
                }
            }
        }
    }

    // ====== epilogue t=T: L1 computes h2(T-1) from frags read at S3(T-1) ======
    if (!isL0) {
        f32x4 a0 = MFMA(Whi[0][0], Bf[0], bias4[0]);
        f32x4 a1 = MFMA(Whi[1][0], Bf[0], bias4[1]);
        f32x4 a2 = MFMA(Whi[2][0], Bf[0], bias4[2]);
        f32x4 a3 = MFMA(Whi[3][0], Bf[0], bias4[3]);
        #pragma unroll
        for (int kc=1; kc<4; ++kc){
            a0 = MFMA(Whi[0][kc], Bf[kc], a0);
            a1 = MFMA(Whi[1][kc], Bf[kc], a1);
            a2 = MFMA(Whi[2][kc], Bf[kc], a2);
            a3 = MFMA(Whi[3][kc], Bf[kc], a3);
        }
        float g0,g1,g2,g3;
        spread_fold(a0,a1,a2,a3,q,g0,g1,g2,g3);
        if (pw) {
            float i_ = sigm2(g0), f_ = sigm2(g1);
            float gg = tanh2(g2), o_ = sigm2(g3);
            cst = fmaf(f_, cst, i_ * gg);
            float h = o_ * tanhc(cst);
            _Float16 hh = (_Float16)h;
            h2p[(T-1) & 3][0][m][u] = hh;      // slot 2999&3 = 3
            h2p[(T-1) & 3][1][m][u] = (_Float16)(h - (float)hh);
        }
    }
    __syncthreads();

    // ---------------- FC epilogue: out[b] = dot(h2(T-1), Wfc) + bfc ----------
    if (wid < NB) {
        float hv = (float)h2p[(T-1) & 3][0][wid][lane]
                 + (float)h2p[(T-1) & 3][1][wid][lane];
        float val = hv * Wfc[lane];
        #pragma unroll
        for (int off = 32; off > 0; off >>= 1)
            val += __shfl_down(val, off, 64);
        if (lane == 0) out[b0 + wid] = val + bfc[0];
    }
}

} // namespace

extern "C" void kernel_launch(void* const* d_in, const int* in_sizes, int n_in,
                              void* d_out, int out_size, void* d_ws, size_t ws_size,
                              hipStream_t stream)
{
    const float* x    = (const float*)d_in[0];
    const float* Wih0 = (const float*)d_in[1];
    const float* Whh0 = (const float*)d_in[2];
    const float* bih0 = (const float*)d_in[3];
    const float* bhh0 = (const float*)d_in[4];
    const float* Wih1 = (const float*)d_in[5];
    const float* Whh1 = (const float*)d_in[6];
    const float* bih1 = (const float*)d_in[7];
    const float* bhh1 = (const float*)d_in[8];
    const float* Wfc  = (const float*)d_in[9];
    const float* bfc  = (const float*)d_in[10];
    float* out = (float*)d_out;

    hipLaunchKernelGGL(lstm_mfB, dim3(512 / NB), dim3(512), 0, stream,
                       x, Wih0, Whh0, bih0, bhh0, Wih1, Whh1, bih1, bhh1,
                       Wfc, bfc, out);
}

// Round 21
// 1762.784 us; speedup vs baseline: 1.1571x; 1.1571x over previous
//
#include <hip/hip_runtime.h>
#include <stdint.h>

namespace {

constexpr int NIN = 21;
constexpr int T   = 3000;
constexpr int NB  = 2;     // batches per block -> 256 blocks = 1 per CU

constexpr float L2E  = 1.4426950408889634f;   // log2(e)
constexpr float L2E2 = 2.8853900817779268f;   // 2*log2(e)

typedef _Float16 f16x8 __attribute__((ext_vector_type(8)));
typedef float    f32x4 __attribute__((ext_vector_type(4)));

__device__ __forceinline__ float frcp(float x){ return __builtin_amdgcn_rcpf(x); }

// RAW v_exp_f32 (2^x). exp2f() lowers to __ocml_exp2_f32 (precise, branchy,
// ~20 extra ops) — that was r20's 1665->2039 regression. The builtin (or a
// plain-VALU asm fallback; normal operand interlocks, NOT a DPP hazard) is
// the single instruction we want.
#if __has_builtin(__builtin_amdgcn_exp2f)
__device__ __forceinline__ float ex2(float x){ return __builtin_amdgcn_exp2f(x); }
#else
__device__ __forceinline__ float ex2(float x){
    float r; asm("v_exp_f32 %0, %1" : "=v"(r) : "v"(x)); return r;
}
#endif
// activations on pre-scaled gates: v = L2E*x (sigm) / L2E2*x (tanh)
__device__ __forceinline__ float sigm2(float v){ return frcp(1.0f + ex2(-v)); }
__device__ __forceinline__ float tanh2(float v){
    return fmaf(-2.0f, frcp(ex2(v) + 1.0f), 1.0f);
}
__device__ __forceinline__ float tanhc(float c){ return tanh2(c * L2E2); }

template<int CTRL>
__device__ __forceinline__ float dppf(float v){
    return __int_as_float(__builtin_amdgcn_update_dpp(
        0, __float_as_int(v), CTRL, 0xF, 0xF, true));
}
// Verified family: row_ror:J => out[i] = in[(i-J)&15]; row_shr:N => out[i] = in[i-N]
constexpr int SHR4  = 0x114;
constexpr int SHR8  = 0x118;
constexpr int SHR12 = 0x11C;
constexpr int ROR14 = 0x12E;   // out[i] = in[(i+2)&15]

#define MFMA(A,B,C) __builtin_amdgcn_mfma_f32_16x16x32_f16((A),(B),(C),0,0,0)

// LDS-visibility barrier WITHOUT vmcnt drain (keeps x prefetch in flight).
#define LDS_BARRIER() asm volatile("s_waitcnt lgkmcnt(0)\n\ts_barrier" ::: "memory")

__device__ __forceinline__ f16x8 ldfrag(const _Float16* p){
    return *reinterpret_cast<const f16x8*>(p);   // aligned 16B LDS read
}
__device__ __forceinline__ void cvt8h(const float* s, f16x8& hi){
    #pragma unroll
    for (int j=0;j<8;++j) hi[j] = (_Float16)s[j];
}

// Verified MFMA layout (r8-r18): D[n][m] = sum_k A[n][k]*B[m][k]
//   A-frag: n = lane&15, k = 32*kc + 8*(lane>>4) + j ; B same
//   D:      m = lane&15, n = 4*(lane>>4) + v
// B cols: 0,1 = batch0/1 Hhi; 2,3 = batch0/1 Hlo; >=4 zero.
// W f16 hi-only, pre-scaled (L2E; L2E2 for gate g).
// gate = D[:,m] + D[:,m+2] = Whi·(Hhi+Hlo). Bias 0.5x·sc in C-init.
// Spread via BUILTIN dpp movs only (r19 lesson: inline-asm DPP reading
// freshly written regs skips mandatory hazard nops -> wrong results).
__device__ __forceinline__ void spread_fold(const f32x4& a0, const f32x4& a1,
                                            const f32x4& a2, const f32x4& a3,
                                            int q, float& g0, float& g1,
                                            float& g2, float& g3){
    float u1,u2,u3;
    u1=dppf<SHR4>(a0[1]); u2=dppf<SHR8>(a0[2]); u3=dppf<SHR12>(a0[3]);
    g0=(q==0)?a0[0]:(q==1)?u1:(q==2)?u2:u3;
    u1=dppf<SHR4>(a1[1]); u2=dppf<SHR8>(a1[2]); u3=dppf<SHR12>(a1[3]);
    g1=(q==0)?a1[0]:(q==1)?u1:(q==2)?u2:u3;
    u1=dppf<SHR4>(a2[1]); u2=dppf<SHR8>(a2[2]); u3=dppf<SHR12>(a2[3]);
    g2=(q==0)?a2[0]:(q==1)?u1:(q==2)?u2:u3;
    u1=dppf<SHR4>(a3[1]); u2=dppf<SHR8>(a3[2]); u3=dppf<SHR12>(a3[3]);
    g3=(q==0)?a3[0]:(q==1)?u1:(q==2)?u2:u3;
    g0 += dppf<ROR14>(g0);
    g1 += dppf<ROR14>(g1);
    g2 += dppf<ROR14>(g2);
    g3 += dppf<ROR14>(g3);
}

__launch_bounds__(512, 2)
__global__ void lstm_mfC(const float* __restrict__ x,
                         const float* __restrict__ Wih0, const float* __restrict__ Whh0,
                         const float* __restrict__ bih0, const float* __restrict__ bhh0,
                         const float* __restrict__ Wih1, const float* __restrict__ Whh1,
                         const float* __restrict__ bih1, const float* __restrict__ bhh1,
                         const float* __restrict__ Wfc,  const float* __restrict__ bfc,
                         float* __restrict__ out)
{
    const int tid  = threadIdx.x;
    const int lane = tid & 63;
    const int wid  = tid >> 6;
    const int c    = lane >> 4;     // k-subchunk 0..3
    const int mcol = lane & 15;
    const int b0   = blockIdx.x * NB;
    const bool isL0 = (wid < 4);
    const int  w    = wid & 3;      // unit range [16w, 16w+16)

    __shared__ __align__(16) _Float16 h1p[4][2][NB][72]; // [slot][plane][batch][unit(+pad)]
    __shared__ __align__(16) _Float16 h2p[4][2][NB][72];
    __shared__ __align__(16) _Float16 xp [4][2][NB][40]; // [slot][plane][batch][feat(+pad)]

    // ----- weights: unified slots, pre-scaled for exp2-based activations -----
    f16x8 Whi[4][4];
    f32x4 bias4[4];
    {
        float tmp[8];
        #pragma unroll
        for (int tau = 0; tau < 4; ++tau) {
            const float sc = (tau == 2) ? L2E2 : L2E;
            const int n = 64*tau + 16*w + mcol;
            if (isL0) {
                #pragma unroll
                for (int j=0;j<8;++j){ int k=8*c+j; tmp[j] = (k<NIN)? sc*Wih0[n*NIN+k] : 0.0f; }
                cvt8h(tmp, Whi[tau][0]);
                #pragma unroll
                for (int kc=0;kc<2;++kc){
                    #pragma unroll
                    for (int j=0;j<8;++j) tmp[j] = sc*Whh0[n*64 + 32*kc + 8*c + j];
                    cvt8h(tmp, Whi[tau][1+kc]);
                }
                #pragma unroll
                for (int j=0;j<8;++j) Whi[tau][3][j] = (_Float16)0.f;
            } else {
                #pragma unroll
                for (int kc=0;kc<2;++kc){
                    #pragma unroll
                    for (int j=0;j<8;++j) tmp[j] = sc*Wih1[n*64 + 32*kc + 8*c + j];
                    cvt8h(tmp, Whi[tau][kc]);
                }
                #pragma unroll
                for (int kc=0;kc<2;++kc){
                    #pragma unroll
                    for (int j=0;j<8;++j) tmp[j] = sc*Whh1[n*64 + 32*kc + 8*c + j];
                    cvt8h(tmp, Whi[tau][2+kc]);
                }
            }
            // bias: 0.5x (both summed cols carry it), scaled
            const int nb = 64*tau + 16*w + 4*c;
            #pragma unroll
            for (int v=0; v<4; ++v)
                bias4[tau][v] = 0.5f * sc * (isL0 ? (bih0[nb+v] + bhh0[nb+v])
                                                  : (bih1[nb+v] + bhh1[nb+v]));
        }
    }

    // ----- LDS zero init (slots 3 / (t-1) double as the t=0 zero states) -----
    {
        uint32_t* p1 = (uint32_t*)&h1p[0][0][0][0];   // 576 u32
        uint32_t* p2 = (uint32_t*)&h2p[0][0][0][0];
        uint32_t* p3 = (uint32_t*)&xp[0][0][0][0];    // 320 u32
        for (int i = tid; i < 576; i += 512){ p1[i]=0u; p2[i]=0u; }
        if (tid < 320) p3[tid] = 0u;
    }
    __syncthreads();

    // ----- x staging: waves 0,1, lane<NIN -> (batch=wid, feat=lane) -----
    const bool stg = (wid < 2) && (lane < NIN);
    const float* xsrc = x + (size_t)(b0 + (wid & 1)) * T * NIN + lane;
    float xq0 = 0.f, xq1 = 0.f, xq2 = 0.f, xq3 = 0.f;
    if (stg){
        float x0 = xsrc[0], x1 = xsrc[NIN];
        _Float16 hh0 = (_Float16)x0;
        xp[0][0][wid][lane] = hh0;
        xp[0][1][wid][lane] = (_Float16)(x0 - (float)hh0);
        _Float16 hh1 = (_Float16)x1;
        xp[1][0][wid][lane] = hh1;
        xp[1][1][wid][lane] = (_Float16)(x1 - (float)hh1);
        xq2 = xsrc[(size_t)2*NIN];   // consumed at t=0 (writes x(2))
        xq3 = xsrc[(size_t)3*NIN];   // consumed at t=1 (writes x(3))
    }
    __syncthreads();

    // ----- B fragments: lane mcol<4 -> batch = mcol&1, plane = mcol>>1 -----
    f16x8 Bf[4];
    #pragma unroll
    for (int kc=0;kc<4;++kc)
        #pragma unroll
        for (int j=0;j<8;++j) Bf[kc][j] = (_Float16)0.f;
    if (isL0 && mcol < 4){
        Bf[0] = ldfrag(&xp[0][mcol>>1][mcol&1][8*c]);   // x(0); h slots stay 0
    }

    float cst = 0.f;
    const int q   = mcol >> 2;
    const int m   = mcol & 1;
    const int pl  = (mcol >> 1) & 1;
    const int u   = 16*w + 4*c + q;
    const bool pw = ((mcol & 2) == 0);

    // ====== main loop: 750 x 4 phases; t = tb+ph in [0, T) ======
    for (int tb = 0; tb < T; tb += 4) {
        #pragma unroll
        for (int ph = 0; ph < 4; ++ph) {
            const int t = tb + ph;

            // ---- S1: issue x(t+4) global load into xq[ph] ----
            if (stg && (t + 4 < T)) {
                float v = xsrc[(size_t)(t+4)*NIN];
                if (ph == 0) xq0 = v; else if (ph == 1) xq1 = v;
                else if (ph == 2) xq2 = v; else xq3 = v;
            }

            // ---- S1: MFMA (Bf from prev phase) ----
            f32x4 a0 = MFMA(Whi[0][0], Bf[0], bias4[0]);
            f32x4 a1 = MFMA(Whi[1][0], Bf[0], bias4[1]);
            f32x4 a2 = MFMA(Whi[2][0], Bf[0], bias4[2]);
            f32x4 a3 = MFMA(Whi[3][0], Bf[0], bias4[3]);
            #pragma unroll
            for (int kc=1; kc<3; ++kc){
                a0 = MFMA(Whi[0][kc], Bf[kc], a0);
                a1 = MFMA(Whi[1][kc], Bf[kc], a1);
                a2 = MFMA(Whi[2][kc], Bf[kc], a2);
                a3 = MFMA(Whi[3][kc], Bf[kc], a3);
            }
            if (!isL0){   // wave-uniform: L1 has 4th chunk
                a0 = MFMA(Whi[0][3], Bf[3], a0);
                a1 = MFMA(Whi[1][3], Bf[3], a1);
                a2 = MFMA(Whi[2][3], Bf[3], a2);
                a3 = MFMA(Whi[3][3], Bf[3], a3);
            }

            // ---- spread (verified builtin-DPP path) + pointwise ----
            float g0,g1,g2,g3;
            spread_fold(a0,a1,a2,a3,q,g0,g1,g2,g3);

            _Float16 hh = (_Float16)0.f, hl = (_Float16)0.f;
            const bool dow = pw && (isL0 || t > 0);
            if (dow) {
                float i_ = sigm2(g0), f_ = sigm2(g1);
                float gg = tanh2(g2), o_ = sigm2(g3);
                cst = fmaf(f_, cst, i_ * gg);
                float h = o_ * tanhc(cst);
                hh = (_Float16)h;
                hl = (_Float16)(h - (float)hh);
            }

            // ---- S2: pre-barrier x-frag read (slot written 2 steps ago,
            //          protected by barrier(t-1); drains at LDS_BARRIER) ----
            if (isL0 && mcol < 4)
                Bf[0] = ldfrag(&xp[(ph+1) & 3][pl][m][8*c]);     // x(t+1)

            // ---- S2: writes ----
            if (dow) {
                if (isL0){
                    h1p[ph & 3][0][m][u] = hh;          // h1(t), slot t&3
                    h1p[ph & 3][1][m][u] = hl;
                } else {
                    h2p[(ph+3) & 3][0][m][u] = hh;      // h2(t-1), slot (t-1)&3
                    h2p[(ph+3) & 3][1][m][u] = hl;
                }
            }
            if (stg && (t + 2 < T)){
                float xv = (ph == 0) ? xq2 : (ph == 1) ? xq3
                         : (ph == 2) ? xq0 : xq1;       // xq[(ph+2)&3] = x(t+2)
                _Float16 xh = (_Float16)xv;
                xp[(ph+2) & 3][0][wid][lane] = xh;
                xp[(ph+2) & 3][1][wid][lane] = (_Float16)(xv - (float)xh);
            }

            LDS_BARRIER();   // writes (and x-frag read) retired; vmcnt NOT drained

            // ---- S3: h fragment reads for step t+1 ----
            if (mcol < 4){
                if (isL0){
                    Bf[1] = ldfrag(&h1p[ph & 3][pl][m][8*c]);        // h1(t)
                    Bf[2] = ldfrag(&h1p[ph & 3][pl][m][32 + 8*c]);
                } else {
                    Bf[0] = ldfrag(&h1p[ph & 3][pl][m][8*c]);        // h1(t)
                    Bf[1] = ldfrag(&h1p[ph & 3][pl][m][32 + 8*c]);
                    Bf[2] = ldfrag(&h2p[(ph+3) & 3][pl][m][8*c]);    // h2(t-1)
                    Bf[3] = ldfrag(&h2p[(ph+3) & 3][pl][m][32 + 8*c]);
                }
            }
        }
    }

    // ====== epilogue t=T: L1 computes h2(T-1) from frags read at S3(T-1) ======
    if (!isL0) {
        f32x4 a0 = MFMA(Whi[0][0], Bf[0], bias4[0]);
        f32x4 a1 = MFMA(Whi[1][0], Bf[0], bias4[1]);
        f32x4 a2 = MFMA(Whi[2][0], Bf[0], bias4[2]);
        f32x4 a3 = MFMA(Whi[3][0], Bf[0], bias4[3]);
        #pragma unroll
        for (int kc=1; kc<4; ++kc){
            a0 = MFMA(Whi[0][kc], Bf[kc], a0);
            a1 = MFMA(Whi[1][kc], Bf[kc], a1);
            a2 = MFMA(Whi[2][kc], Bf[kc], a2);
            a3 = MFMA(Whi[3][kc], Bf[kc], a3);
        }
        float g0,g1,g2,g3;
        spread_fold(a0,a1,a2,a3,q,g0,g1,g2,g3);
        if (pw) {
            float i_ = sigm2(g0), f_ = sigm2(g1);
            float gg = tanh2(g2), o_ = sigm2(g3);
            cst = fmaf(f_, cst, i_ * gg);
            float h = o_ * tanhc(cst);
            _Float16 hh = (_Float16)h;
            h2p[(T-1) & 3][0][m][u] = hh;      // slot 2999&3 = 3
            h2p[(T-1) & 3][1][m][u] = (_Float16)(h - (float)hh);
        }
    }
    __syncthreads();

    // ---------------- FC epilogue: out[b] = dot(h2(T-1), Wfc) + bfc ----------
    if (wid < NB) {
        float hv = (float)h2p[(T-1) & 3][0][wid][lane]
                 + (float)h2p[(T-1) & 3][1][wid][lane];
        float val = hv * Wfc[lane];
        #pragma unroll
        for (int off = 32; off > 0; off >>= 1)
            val += __shfl_down(val, off, 64);
        if (lane == 0) out[b0 + wid] = val + bfc[0];
    }
}

} // namespace

extern "C" void kernel_launch(void* const* d_in, const int* in_sizes, int n_in,
                              void* d_out, int out_size, void* d_ws, size_t ws_size,
                              hipStream_t stream)
{
    const float* x    = (const float*)d_in[0];
    const float* Wih0 = (const float*)d_in[1];
    const float* Whh0 = (const float*)d_in[2];
    const float* bih0 = (const float*)d_in[3];
    const float* bhh0 = (const float*)d_in[4];
    const float* Wih1 = (const float*)d_in[5];
    const float* Whh1 = (const float*)d_in[6];
    const float* bih1 = (const float*)d_in[7];
    const float* bhh1 = (const float*)d_in[8];
    const float* Wfc  = (const float*)d_in[9];
    const float* bfc  = (const float*)d_in[10];
    float* out = (float*)d_out;

    hipLaunchKernelGGL(lstm_mfC, dim3(512 / NB), dim3(512), 0, stream,
                       x, Wih0, Whh0, bih0, bhh0, Wih1, Whh1, bih1, bhh1,
                       Wfc, bfc, out);
}

// Round 22
// 1669.413 us; speedup vs baseline: 1.2218x; 1.0559x over previous
//
#include <hip/hip_runtime.h>
#include <stdint.h>

namespace {

constexpr int NIN = 21;
constexpr int T   = 3000;
constexpr int NB  = 2;     // batches per block -> 256 blocks = 1 per CU

typedef _Float16 f16x8 __attribute__((ext_vector_type(8)));
typedef float    f32x4 __attribute__((ext_vector_type(4)));

__device__ __forceinline__ float frcp(float x){ return __builtin_amdgcn_rcpf(x); }
__device__ __forceinline__ float sigm(float v){ return frcp(1.0f + __expf(-v)); }
__device__ __forceinline__ float tanh_fast(float v){
    return fmaf(-2.0f, frcp(__expf(2.0f*v) + 1.0f), 1.0f);
}

template<int CTRL>
__device__ __forceinline__ float dppf(float v){
    return __int_as_float(__builtin_amdgcn_update_dpp(
        0, __float_as_int(v), CTRL, 0xF, 0xF, true));
}
// Verified family: row_ror:J => out[i] = in[(i-J)&15]; row_shr:N => out[i] = in[i-N]
constexpr int SHR4  = 0x114;
constexpr int SHR8  = 0x118;
constexpr int SHR12 = 0x11C;
constexpr int ROR14 = 0x12E;   // out[i] = in[(i+2)&15]

#define MFMA(A,B,C) __builtin_amdgcn_mfma_f32_16x16x32_f16((A),(B),(C),0,0,0)

// LDS-visibility barrier WITHOUT vmcnt drain (keeps x prefetch in flight).
#define LDS_BARRIER() asm volatile("s_waitcnt lgkmcnt(0)\n\ts_barrier" ::: "memory")

__device__ __forceinline__ f16x8 ldfrag(const _Float16* p){
    return *reinterpret_cast<const f16x8*>(p);   // aligned 16B LDS read
}
__device__ __forceinline__ void cvt8h(const float* s, f16x8& hi){
    #pragma unroll
    for (int j=0;j<8;++j) hi[j] = (_Float16)s[j];
}

// Verified MFMA layout (r8-r18): D[n][m] = sum_k A[n][k]*B[m][k]
//   A-frag: n = lane&15, k = 32*kc + 8*(lane>>4) + j ; B same
//   D:      m = lane&15, n = 4*(lane>>4) + v
// B cols: 0,1 = batch0/1 Hhi; 2,3 = batch0/1 Hlo; >=4 zero.
// W f16 hi-only (absmax 4.9e-4 vs 2.37e-3 threshold).
// gate = D[:,m] + D[:,m+2] = Whi·(Hhi+Hlo). Bias halved in C-init.
// Spread via BUILTIN dpp movs only (r19 lesson: inline-asm DPP reading
// freshly written regs skips mandatory hazard nops -> wrong results).
// Activations via __expf (native v_exp path); exp2-prescale variants
// (r20 ocml, r21 builtin/asm) both measured slower — keep __expf.
__device__ __forceinline__ void spread_fold(const f32x4& a0, const f32x4& a1,
                                            const f32x4& a2, const f32x4& a3,
                                            int q, float& g0, float& g1,
                                            float& g2, float& g3){
    float u1,u2,u3;
    u1=dppf<SHR4>(a0[1]); u2=dppf<SHR8>(a0[2]); u3=dppf<SHR12>(a0[3]);
    g0=(q==0)?a0[0]:(q==1)?u1:(q==2)?u2:u3;
    u1=dppf<SHR4>(a1[1]); u2=dppf<SHR8>(a1[2]); u3=dppf<SHR12>(a1[3]);
    g1=(q==0)?a1[0]:(q==1)?u1:(q==2)?u2:u3;
    u1=dppf<SHR4>(a2[1]); u2=dppf<SHR8>(a2[2]); u3=dppf<SHR12>(a2[3]);
    g2=(q==0)?a2[0]:(q==1)?u1:(q==2)?u2:u3;
    u1=dppf<SHR4>(a3[1]); u2=dppf<SHR8>(a3[2]); u3=dppf<SHR12>(a3[3]);
    g3=(q==0)?a3[0]:(q==1)?u1:(q==2)?u2:u3;
    g0 += dppf<ROR14>(g0);
    g1 += dppf<ROR14>(g1);
    g2 += dppf<ROR14>(g2);
    g3 += dppf<ROR14>(g3);
}

// Single-barrier schedule, 4-deep buffers (r18 champion, 1665 us).
// Conflict audit (read@S3(t) vs next write of same slot): h1 slot t&3 ->
// S2(t+4) (3 barriers later); h2 slot (t-1)&3 -> S2(t+4); x slot (t+1)&3 ->
// S2(t+3). All >=1 full barrier after the read => race-free for any drift.
__launch_bounds__(512, 2)
__global__ void lstm_mf9(const float* __restrict__ x,
                         const float* __restrict__ Wih0, const float* __restrict__ Whh0,
                         const float* __restrict__ bih0, const float* __restrict__ bhh0,
                         const float* __restrict__ Wih1, const float* __restrict__ Whh1,
                         const float* __restrict__ bih1, const float* __restrict__ bhh1,
                         const float* __restrict__ Wfc,  const float* __restrict__ bfc,
                         float* __restrict__ out)
{
    const int tid  = threadIdx.x;
    const int lane = tid & 63;
    const int wid  = tid >> 6;
    const int c    = lane >> 4;     // k-subchunk 0..3
    const int mcol = lane & 15;
    const int b0   = blockIdx.x * NB;
    const bool isL0 = (wid < 4);
    const int  w    = wid & 3;      // unit range [16w, 16w+16)

    __shared__ __align__(16) _Float16 h1p[4][2][NB][72]; // [slot][plane][batch][unit(+pad)]
    __shared__ __align__(16) _Float16 h2p[4][2][NB][72];
    __shared__ __align__(16) _Float16 xp [4][2][NB][40]; // [slot][plane][batch][feat(+pad)]

    // ----- weights: unified slots shared by roles (hi plane only) -----
    f16x8 Whi[4][4];
    f32x4 bias4[4];
    {
        float tmp[8];
        #pragma unroll
        for (int tau = 0; tau < 4; ++tau) {
            const int n = 64*tau + 16*w + mcol;
            if (isL0) {
                #pragma unroll
                for (int j=0;j<8;++j){ int k=8*c+j; tmp[j] = (k<NIN)? Wih0[n*NIN+k] : 0.0f; }
                cvt8h(tmp, Whi[tau][0]);
                #pragma unroll
                for (int kc=0;kc<2;++kc){
                    #pragma unroll
                    for (int j=0;j<8;++j) tmp[j] = Whh0[n*64 + 32*kc + 8*c + j];
                    cvt8h(tmp, Whi[tau][1+kc]);
                }
                #pragma unroll
                for (int j=0;j<8;++j) Whi[tau][3][j] = (_Float16)0.f;
            } else {
                #pragma unroll
                for (int kc=0;kc<2;++kc){
                    #pragma unroll
                    for (int j=0;j<8;++j) tmp[j] = Wih1[n*64 + 32*kc + 8*c + j];
                    cvt8h(tmp, Whi[tau][kc]);
                }
                #pragma unroll
                for (int kc=0;kc<2;++kc){
                    #pragma unroll
                    for (int j=0;j<8;++j) tmp[j] = Whh1[n*64 + 32*kc + 8*c + j];
                    cvt8h(tmp, Whi[tau][2+kc]);
                }
            }
            const int nb = 64*tau + 16*w + 4*c;
            #pragma unroll
            for (int v=0; v<4; ++v)
                bias4[tau][v] = 0.5f * (isL0 ? (bih0[nb+v] + bhh0[nb+v])
                                             : (bih1[nb+v] + bhh1[nb+v]));
        }
    }

    // ----- LDS zero init (all 4 slots; slots 3/(t-1) double as zero states) -----
    {
        uint32_t* p1 = (uint32_t*)&h1p[0][0][0][0];   // 2304B = 576 u32
        uint32_t* p2 = (uint32_t*)&h2p[0][0][0][0];
        uint32_t* p3 = (uint32_t*)&xp[0][0][0][0];    // 1280B = 320 u32
        for (int i = tid; i < 576; i += 512){ p1[i]=0u; p2[i]=0u; }
        if (tid < 320) p3[tid] = 0u;
    }
    __syncthreads();

    // ----- x staging: waves 0,1, lane<NIN -> (batch=wid, feat=lane) -----
    const bool stg = (wid < 2) && (lane < NIN);
    const float* xsrc = x + (size_t)(b0 + (wid & 1)) * T * NIN + lane;
    // static prefetch regs: xq[p] holds x loaded at phase p (= x(p+4) in steady
    // state); consumed (LDS write) 2 phases later -> vmcnt wait deferred.
    float xq0 = 0.f, xq1 = 0.f, xq2 = 0.f, xq3 = 0.f;
    if (stg){
        float x0 = xsrc[0], x1 = xsrc[NIN];
        _Float16 hh0 = (_Float16)x0;
        xp[0][0][wid][lane] = hh0;
        xp[0][1][wid][lane] = (_Float16)(x0 - (float)hh0);
        _Float16 hh1 = (_Float16)x1;
        xp[1][0][wid][lane] = hh1;
        xp[1][1][wid][lane] = (_Float16)(x1 - (float)hh1);
        xq2 = xsrc[(size_t)2*NIN];   // consumed at t=0 (writes x(2))
        xq3 = xsrc[(size_t)3*NIN];   // consumed at t=1 (writes x(3))
    }
    __syncthreads();

    // ----- B fragments: lane mcol<4 -> batch = mcol&1, plane = mcol>>1 -----
    f16x8 Bf[4];
    #pragma unroll
    for (int kc=0;kc<4;++kc)
        #pragma unroll
        for (int j=0;j<8;++j) Bf[kc][j] = (_Float16)0.f;
    if (isL0 && mcol < 4){
        Bf[0] = ldfrag(&xp[0][mcol>>1][mcol&1][8*c]);   // x(0); h slots stay 0
    }

    float cst = 0.f;
    const int q   = mcol >> 2;
    const int m   = mcol & 1;
    const int pl  = (mcol >> 1) & 1;
    const int u   = 16*w + 4*c + q;
    const bool pw = ((mcol & 2) == 0);

    // ====== main loop: 750 x 4 phases; t = tb+ph in [0, T) ======
    for (int tb = 0; tb < T; tb += 4) {
        #pragma unroll
        for (int ph = 0; ph < 4; ++ph) {
            const int t = tb + ph;

            // ---- S1: issue x(t+4) load into xq[ph] (no copies; static name) --
            if (stg && (t + 4 < T)) {
                float v = xsrc[(size_t)(t+4)*NIN];
                if (ph == 0) xq0 = v; else if (ph == 1) xq1 = v;
                else if (ph == 2) xq2 = v; else xq3 = v;
            }

            // ---- S1: MFMA (Bf from S3 of prev phase) + glue ----
            f32x4 a0 = MFMA(Whi[0][0], Bf[0], bias4[0]);
            f32x4 a1 = MFMA(Whi[1][0], Bf[0], bias4[1]);
            f32x4 a2 = MFMA(Whi[2][0], Bf[0], bias4[2]);
            f32x4 a3 = MFMA(Whi[3][0], Bf[0], bias4[3]);
            #pragma unroll
            for (int kc=1; kc<3; ++kc){
                a0 = MFMA(Whi[0][kc], Bf[kc], a0);
                a1 = MFMA(Whi[1][kc], Bf[kc], a1);
                a2 = MFMA(Whi[2][kc], Bf[kc], a2);
                a3 = MFMA(Whi[3][kc], Bf[kc], a3);
            }
            if (!isL0){   // wave-uniform branch: L1 has 4th chunk
                a0 = MFMA(Whi[0][3], Bf[3], a0);
                a1 = MFMA(Whi[1][3], Bf[3], a1);
                a2 = MFMA(Whi[2][3], Bf[3], a2);
                a3 = MFMA(Whi[3][3], Bf[3], a3);
            }
            float g0,g1,g2,g3;
            spread_fold(a0,a1,a2,a3,q,g0,g1,g2,g3);

            _Float16 hh = (_Float16)0.f, hl = (_Float16)0.f;
            const bool dow = pw && (isL0 || t > 0);
            if (dow) {
                float i_ = sigm(g0), f_ = sigm(g1);
                float gg = tanh_fast(g2), o_ = sigm(g3);
                cst = fmaf(f_, cst, i_ * gg);
                float h = o_ * tanh_fast(cst);
                hh = (_Float16)h;
                hl = (_Float16)(h - (float)hh);
            }

            // ---- S2: writes ----
            if (dow) {
                if (isL0){
                    h1p[ph & 3][0][m][u] = hh;          // h1(t), slot t&3
                    h1p[ph & 3][1][m][u] = hl;
                } else {
                    h2p[(ph+3) & 3][0][m][u] = hh;      // h2(t-1), slot (t-1)&3
                    h2p[(ph+3) & 3][1][m][u] = hl;
                }
            }
            if (stg && (t + 2 < T)){
                float xv = (ph == 0) ? xq2 : (ph == 1) ? xq3
                         : (ph == 2) ? xq0 : xq1;       // xq[(ph+2)&3] = x(t+2)
                _Float16 xh = (_Float16)xv;
                xp[(ph+2) & 3][0][wid][lane] = xh;
                xp[(ph+2) & 3][1][wid][lane] = (_Float16)(xv - (float)xh);
            }

            LDS_BARRIER();   // writes visible; vmcnt NOT drained

            // ---- S3: fragment reads for step t+1 ----
            if (mcol < 4){
                if (isL0){
                    Bf[0] = ldfrag(&xp[(ph+1) & 3][pl][m][8*c]);     // x(t+1)
                    Bf[1] = ldfrag(&h1p[ph & 3][pl][m][8*c]);        // h1(t)
                    Bf[2] = ldfrag(&h1p[ph & 3][pl][m][32 + 8*c]);
                } else {
                    Bf[0] = ldfrag(&h1p[ph & 3][pl][m][8*c]);        // h1(t)
                    Bf[1] = ldfrag(&h1p[ph & 3][pl][m][32 + 8*c]);
                    Bf[2] = ldfrag(&h2p[(ph+3) & 3][pl][m][8*c]);    // h2(t-1)
                    Bf[3] = ldfrag(&h2p[(ph+3) & 3][pl][m][32 + 8*c]);
                }
            }
        }
    }

    // ====== epilogue t=T: L1 computes h2(T-1) from frags read at S3(T-1) ======
    if (!isL0) {
        f32x4 a0 = MFMA(Whi[0][0], Bf[0], bias4[0]);
        f32x4 a1 = MFMA(Whi[1][0], Bf[0], bias4[1]);
        f32x4 a2 = MFMA(Whi[2][0], Bf[0], bias4[2]);
        f32x4 a3 = MFMA(Whi[3][0], Bf[0], bias4[3]);
        #pragma unroll
        for (int kc=1; kc<4; ++kc){
            a0 = MFMA(Whi[0][kc], Bf[kc], a0);
            a1 = MFMA(Whi[1][kc], Bf[kc], a1);
            a2 = MFMA(Whi[2][kc], Bf[kc], a2);
            a3 = MFMA(Whi[3][kc], Bf[kc], a3);
        }
        float g0,g1,g2,g3;
        spread_fold(a0,a1,a2,a3,q,g0,g1,g2,g3);
        if (pw) {
            float i_ = sigm(g0), f_ = sigm(g1);
            float gg = tanh_fast(g2), o_ = sigm(g3);
            cst = fmaf(f_, cst, i_ * gg);
            float h = o_ * tanh_fast(cst);
            _Float16 hh = (_Float16)h;
            h2p[(T-1) & 3][0][m][u] = hh;      // slot 2999&3 = 3
            h2p[(T-1) & 3][1][m][u] = (_Float16)(h - (float)hh);
        }
    }
    __syncthreads();

    // ---------------- FC epilogue: out[b] = dot(h2(T-1), Wfc) + bfc ----------
    if (wid < NB) {
        float hv = (float)h2p[(T-1) & 3][0][wid][lane]
                 + (float)h2p[(T-1) & 3][1][wid][lane];
        float val = hv * Wfc[lane];
        #pragma unroll
        for (int off = 32; off > 0; off >>= 1)
            val += __shfl_down(val, off, 64);
        if (lane == 0) out[b0 + wid] = val + bfc[0];
    }
}

} // namespace

extern "C" void kernel_launch(void* const* d_in, const int* in_sizes, int n_in,
                              void* d_out, int out_size, void* d_ws, size_t ws_size,
                              hipStream_t stream)
{
    const float* x    = (const float*)d_in[0];
    const float* Wih0 = (const float*)d_in[1];
    const float* Whh0 = (const float*)d_in[2];
    const float* bih0 = (const float*)d_in[3];
    const float* bhh0 = (const float*)d_in[4];
    const float* Wih1 = (const float*)d_in[5];
    const float* Whh1 = (const float*)d_in[6];
    const float* bih1 = (const float*)d_in[7];
    const float* bhh1 = (const float*)d_in[8];
    const float* Wfc  = (const float*)d_in[9];
    const float* bfc  = (const float*)d_in[10];
    float* out = (float*)d_out;

    hipLaunchKernelGGL(lstm_mf9, dim3(512 / NB), dim3(512), 0, stream,
                       x, Wih0, Whh0, bih0, bhh0, Wih1, Whh1, bih1, bhh1,
                       Wfc, bfc, out);
}